// Round 7
// baseline (354.400 us; speedup 1.0000x reference)
//
#include <hip/hip_runtime.h>
#include <math.h>

#define NB 64
#define NL 4096
#define ND 512
#define NE 256
#define NV 32000
#define NX 768            // NE + ND
#define CHUNKS 32         // attention L-chunks per batch
#define RPC (NL / CHUNKS) // 128 rows per chunk
#define RPW (RPC / 4)     // 32 rows per wave
#define NV4 (NV / 4)      // 8000 float4 per vocab row

#define GK_KS 4           // k-split for gates (768 = 4*192)
#define GK_KL 192
#define WE_KS 4           // k-split for W_e   (512 = 4*128)
#define WE_KL 128
#define WO_KS 4           // k-split for W_out (1024 = 4*256)
#define WO_KL 256

// ---------------------------------------------------------------- argmax ----
__global__ void k_argmax(const float* __restrict__ y_prev, int* __restrict__ tok) {
    int b = blockIdx.x, tid = threadIdx.x, lane = tid & 63, wave = tid >> 6;
    const float4* row = (const float4*)(y_prev + (size_t)b * NV);
    float best = -INFINITY; int bi = 0x7fffffff;
    for (int v4 = tid; v4 < NV4; v4 += 1024) {
        float4 x = row[v4];
        int base = v4 * 4;
        if (x.x > best) { best = x.x; bi = base; }
        if (x.y > best) { best = x.y; bi = base + 1; }
        if (x.z > best) { best = x.z; bi = base + 2; }
        if (x.w > best) { best = x.w; bi = base + 3; }
    }
    #pragma unroll
    for (int off = 32; off > 0; off >>= 1) {
        float ob = __shfl_xor(best, off, 64);
        int   oi = __shfl_xor(bi, off, 64);
        if (ob > best || (ob == best && oi < bi)) { best = ob; bi = oi; }
    }
    __shared__ float sv[16]; __shared__ int si[16];
    if (lane == 0) { sv[wave] = best; si[wave] = bi; }
    __syncthreads();
    if (tid == 0) {
        float bb = sv[0]; int ii = si[0];
        for (int w = 1; w < 16; ++w)
            if (sv[w] > bb || (sv[w] == bb && si[w] < ii)) { bb = sv[w]; ii = si[w]; }
        tok[b] = ii;
    }
}

// ----------------------- gates GEMM, split-K, float4 W loads ----------------
__global__ void k_gates(const float* __restrict__ embedding, const float* __restrict__ out_prev,
                        const int* __restrict__ tok,
                        const float* __restrict__ W_f, const float* __restrict__ W_i,
                        const float* __restrict__ W_g, const float* __restrict__ W_o,
                        float* __restrict__ gp) {
    __shared__ float xs[16][GK_KL];
    int tid = threadIdx.x;
    int cc = blockIdx.x, bg = blockIdx.y, ks = blockIdx.z;
    int k0 = ks * GK_KL;
    for (int e = tid; e < 16 * GK_KL; e += 256) {
        int bi = e / GK_KL, kk = e - bi * GK_KL;
        int b = bg * 16 + bi, k = k0 + kk;
        xs[bi][kk] = (k < NE) ? embedding[(size_t)tok[b] * NE + k]
                              : out_prev[(size_t)b * ND + (k - NE)];
    }
    __syncthreads();
    int ct = tid & 63, bs = tid >> 6;
    int gate = cc >> 1;
    int d = (cc & 1) * 256 + ct * 4;
    const float* W = (gate == 0) ? W_f : (gate == 1) ? W_i : (gate == 2) ? W_g : W_o;
    const float4* Wp = (const float4*)(W + (size_t)k0 * ND + d);
    float acc[4][4] = {};
    #pragma unroll 4
    for (int kk = 0; kk < GK_KL; ++kk) {
        float4 w4 = Wp[kk * (ND / 4)];
        #pragma unroll
        for (int i = 0; i < 4; ++i) {
            float xv = xs[bs * 4 + i][kk];
            acc[i][0] += xv * w4.x; acc[i][1] += xv * w4.y;
            acc[i][2] += xv * w4.z; acc[i][3] += xv * w4.w;
        }
    }
    #pragma unroll
    for (int i = 0; i < 4; ++i) {
        int b = bg * 16 + bs * 4 + i;
        float4 st = make_float4(acc[i][0], acc[i][1], acc[i][2], acc[i][3]);
        *(float4*)&gp[(((size_t)ks * 4 + gate) * NB + b) * ND + d] = st;
    }
}

// ------------------------- LSTM pointwise + gate k-reduce -------------------
__global__ void k_lstm(const float* __restrict__ gp, const float* __restrict__ c_prev,
                       const float* __restrict__ b_f, const float* __restrict__ b_i,
                       const float* __restrict__ b_g, const float* __restrict__ b_o,
                       float* __restrict__ h_out, float* __restrict__ c_out) {
    int idx = blockIdx.x * 256 + threadIdx.x;  // 0..32767
    int b = idx >> 9, d = idx & 511;
    float F = b_f[d], I = b_i[d], G = b_g[d], O = b_o[d];
    #pragma unroll
    for (int ks = 0; ks < GK_KS; ++ks) {
        F += gp[(((size_t)ks * 4 + 0) * NB + b) * ND + d];
        I += gp[(((size_t)ks * 4 + 1) * NB + b) * ND + d];
        G += gp[(((size_t)ks * 4 + 2) * NB + b) * ND + d];
        O += gp[(((size_t)ks * 4 + 3) * NB + b) * ND + d];
    }
    float f = 1.f / (1.f + __expf(-F));
    float i = 1.f / (1.f + __expf(-I));
    float g = tanhf(G);
    float o = 1.f / (1.f + __expf(-O));
    float c = c_prev[idx] * f + i * g;
    float h = tanhf(c) * o;
    h_out[idx] = h;
    c_out[idx] = c;
}

// --------------------- b = h @ W_e, split-K, float4 W loads -----------------
__global__ void k_we(const float* __restrict__ h, const float* __restrict__ W_e,
                     float* __restrict__ wp) {
    __shared__ float hs[16][WE_KL];
    int tid = threadIdx.x;
    int cc = blockIdx.x, bg = blockIdx.y, ks = blockIdx.z;
    int k0 = ks * WE_KL;
    for (int e = tid; e < 16 * WE_KL; e += 256) {
        int bi = e >> 7, kk = e & 127;
        hs[bi][kk] = h[(size_t)(bg * 16 + bi) * ND + k0 + kk];
    }
    __syncthreads();
    int ct = tid & 63, bs = tid >> 6;
    int col = cc * 256 + ct * 4;
    const float4* Wp = (const float4*)(W_e + (size_t)k0 * ND + col);
    float acc[4][4] = {};
    #pragma unroll 4
    for (int kk = 0; kk < WE_KL; ++kk) {
        float4 w4 = Wp[kk * (ND / 4)];
        #pragma unroll
        for (int i = 0; i < 4; ++i) {
            float xv = hs[bs * 4 + i][kk];
            acc[i][0] += xv * w4.x; acc[i][1] += xv * w4.y;
            acc[i][2] += xv * w4.z; acc[i][3] += xv * w4.w;
        }
    }
    #pragma unroll
    for (int i = 0; i < 4; ++i) {
        int b = bg * 16 + bs * 4 + i;
        float4 st = make_float4(acc[i][0], acc[i][1], acc[i][2], acc[i][3]);
        *(float4*)&wp[((size_t)ks * NB + b) * ND + col] = st;
    }
}

// --------------------------- fused attention: online softmax + context ------
// grid NB*CHUNKS blocks, 256 thr (4 waves). featureGrid read exactly once.
// Contiguous-half loads (lane*4 and 256+lane*4); 4-row groups, ILP'd butterflies.
#define DOT8(VA, VB)                                                          \
    ((VA).x * bs0.x + (VA).y * bs0.y + (VA).z * bs0.z + (VA).w * bs0.w +      \
     (VB).x * bs1.x + (VB).y * bs1.y + (VB).z * bs1.z + (VB).w * bs1.w)

#define ONLINE(E, VA, VB) do {                                                \
    if ((E) > m) {                                                            \
        float sc_ = __expf(m - (E));                                          \
        s *= sc_;                                                             \
        zA.x *= sc_; zA.y *= sc_; zA.z *= sc_; zA.w *= sc_;                   \
        zB.x *= sc_; zB.y *= sc_; zB.z *= sc_; zB.w *= sc_;                   \
        m = (E);                                                              \
    }                                                                         \
    float w_ = __expf((E) - m);                                               \
    s += w_;                                                                  \
    zA.x += w_ * (VA).x; zA.y += w_ * (VA).y;                                 \
    zA.z += w_ * (VA).z; zA.w += w_ * (VA).w;                                 \
    zB.x += w_ * (VB).x; zB.y += w_ * (VB).y;                                 \
    zB.z += w_ * (VB).z; zB.w += w_ * (VB).w;                                 \
  } while (0)

#define ATTN_GROUP(CA, CB, NA, NBUF, GNEXT, HAS) do {                         \
    if (HAS) {                                                                \
        _Pragma("unroll")                                                     \
        for (int r_ = 0; r_ < 4; ++r_) {                                      \
            const float* p_ = rowbase + ((GNEXT) * 4 + r_) * ND;              \
            NA[r_]   = *(const float4*)(p_ + lo4);                            \
            NBUF[r_] = *(const float4*)(p_ + 256 + lo4);                      \
        }                                                                     \
    }                                                                         \
    float e0_ = DOT8(CA[0], CB[0]);                                           \
    float e1_ = DOT8(CA[1], CB[1]);                                           \
    float e2_ = DOT8(CA[2], CB[2]);                                           \
    float e3_ = DOT8(CA[3], CB[3]);                                           \
    _Pragma("unroll")                                                         \
    for (int off_ = 32; off_ > 0; off_ >>= 1) {                               \
        e0_ += __shfl_xor(e0_, off_, 64);                                     \
        e1_ += __shfl_xor(e1_, off_, 64);                                     \
        e2_ += __shfl_xor(e2_, off_, 64);                                     \
        e3_ += __shfl_xor(e3_, off_, 64);                                     \
    }                                                                         \
    ONLINE(e0_, CA[0], CB[0]);                                                \
    ONLINE(e1_, CA[1], CB[1]);                                                \
    ONLINE(e2_, CA[2], CB[2]);                                                \
    ONLINE(e3_, CA[3], CB[3]);                                                \
  } while (0)

__global__ void k_attn(const float* __restrict__ fg, const float* __restrict__ wp,
                       float* __restrict__ partM, float* __restrict__ partS,
                       float* __restrict__ partZ) {
    int blk = blockIdx.x;
    int b = blk / CHUNKS, chunk = blk - b * CHUNKS;
    int tid = threadIdx.x, wave = tid >> 6, lane = tid & 63;
    int lo4 = lane * 4;
    float4 bs0 = make_float4(0.f, 0.f, 0.f, 0.f), bs1 = bs0;
    #pragma unroll
    for (int ks = 0; ks < WE_KS; ++ks) {
        const float* p = wp + ((size_t)ks * NB + b) * ND;
        float4 a = *(const float4*)(p + lo4);
        float4 c = *(const float4*)(p + 256 + lo4);
        bs0.x += a.x; bs0.y += a.y; bs0.z += a.z; bs0.w += a.w;
        bs1.x += c.x; bs1.y += c.y; bs1.z += c.z; bs1.w += c.w;
    }
    const float* rowbase = fg + ((size_t)b * NL + (size_t)chunk * RPC + wave * RPW) * ND;
    float m = -INFINITY, s = 0.f;
    float4 zA = make_float4(0.f, 0.f, 0.f, 0.f), zB = zA;
    float4 gA[4], gB[4], hA[4], hB[4];
    #pragma unroll
    for (int r = 0; r < 4; ++r) {
        gA[r] = *(const float4*)(rowbase + r * ND + lo4);
        gB[r] = *(const float4*)(rowbase + r * ND + 256 + lo4);
    }
    // 8 groups of 4 rows (RPW = 32), ping-pong buffers, prefetch distance 1 group
    ATTN_GROUP(gA, gB, hA, hB, 1, true);
    ATTN_GROUP(hA, hB, gA, gB, 2, true);
    ATTN_GROUP(gA, gB, hA, hB, 3, true);
    ATTN_GROUP(hA, hB, gA, gB, 4, true);
    ATTN_GROUP(gA, gB, hA, hB, 5, true);
    ATTN_GROUP(hA, hB, gA, gB, 6, true);
    ATTN_GROUP(gA, gB, hA, hB, 7, true);
    ATTN_GROUP(hA, hB, gA, gB, 0, false);

    __shared__ float wm[4], wsum[4], wz[4][ND];
    float* zp = &wz[wave][0];
    *(float4*)(zp + lo4) = zA;
    *(float4*)(zp + 256 + lo4) = zB;
    if (lane == 0) { wm[wave] = m; wsum[wave] = s; }
    __syncthreads();
    float M = fmaxf(fmaxf(wm[0], wm[1]), fmaxf(wm[2], wm[3]));
    float e0 = __expf(wm[0] - M), e1 = __expf(wm[1] - M), e2 = __expf(wm[2] - M), e3 = __expf(wm[3] - M);
    if (tid == 0) {
        partM[blk] = M;
        partS[blk] = wsum[0] * e0 + wsum[1] * e1 + wsum[2] * e2 + wsum[3] * e3;
    }
    for (int d = tid; d < ND; d += 256)
        partZ[(size_t)blk * ND + d] = wz[0][d] * e0 + wz[1][d] * e1 + wz[2][d] * e2 + wz[3][d] * e3;
}

// ---------------------------------------------- combine chunk partials → z --
__global__ void k_zcomb(const float* __restrict__ partM, const float* __restrict__ partS,
                        const float* __restrict__ partZ, float* __restrict__ z) {
    int b = blockIdx.x, tid = threadIdx.x;
    float M = -INFINITY;
    #pragma unroll
    for (int j = 0; j < CHUNKS; ++j) M = fmaxf(M, partM[b * CHUNKS + j]);
    float w[CHUNKS]; float S = 0.f;
    #pragma unroll
    for (int j = 0; j < CHUNKS; ++j) { w[j] = __expf(partM[b * CHUNKS + j] - M); S += partS[b * CHUNKS + j] * w[j]; }
    float inv = 1.f / S;
    for (int d = tid; d < ND; d += 256) {
        float acc = 0.f;
        #pragma unroll
        for (int j = 0; j < CHUNKS; ++j) acc += w[j] * partZ[((size_t)b * CHUNKS + j) * ND + d];
        z[(size_t)b * ND + d] = acc * inv;
    }
}

// ----------------- [h,z] @ W_out, split-K, float4 W loads -------------------
__global__ void k_wout(const float* __restrict__ h, const float* __restrict__ z,
                       const float* __restrict__ W_out, float* __restrict__ op) {
    __shared__ float hzs[16][WO_KL];
    int tid = threadIdx.x;
    int cc = blockIdx.x, bg = blockIdx.y, ks = blockIdx.z;
    int k0 = ks * WO_KL;
    for (int e = tid; e < 16 * WO_KL; e += 256) {
        int bi = e >> 8, kk = e & 255;
        int b = bg * 16 + bi, k = k0 + kk;
        hzs[bi][kk] = (k < ND) ? h[(size_t)b * ND + k] : z[(size_t)b * ND + (k - ND)];
    }
    __syncthreads();
    int ct = tid & 63, bs = tid >> 6;
    int col = cc * 256 + ct * 4;
    const float4* Wp = (const float4*)(W_out + (size_t)k0 * ND + col);
    float acc[4][4] = {};
    #pragma unroll 4
    for (int kk = 0; kk < WO_KL; ++kk) {
        float4 w4 = Wp[kk * (ND / 4)];
        #pragma unroll
        for (int i = 0; i < 4; ++i) {
            float xv = hzs[bs * 4 + i][kk];
            acc[i][0] += xv * w4.x; acc[i][1] += xv * w4.y;
            acc[i][2] += xv * w4.z; acc[i][3] += xv * w4.w;
        }
    }
    #pragma unroll
    for (int i = 0; i < 4; ++i) {
        int b = bg * 16 + bs * 4 + i;
        float4 st = make_float4(acc[i][0], acc[i][1], acc[i][2], acc[i][3]);
        *(float4*)&op[((size_t)ks * NB + b) * ND + col] = st;
    }
}

// --------------------------------------------- logits = out @ W_y -----------
// 250 blocks x 512 thr. W_y tile staged into LDS (HBM-read exactly once);
// os staged with fused op-reduce + tanh (replaces k_outfin / outT).
__global__ __launch_bounds__(512) void k_logits(const float* __restrict__ op,
                                                const float* __restrict__ W_y,
                                                float* __restrict__ ylog) {
    __shared__ float4 wsy[64][32];   // [dd][c4] 32 KB
    __shared__ float  os[64][64];    // [dd][b]  16 KB
    int tid = threadIdx.x;
    int cg = tid & 31;               // 32 col-groups x 4 cols = 128 cols
    int bq = tid >> 5;               // 16 batch-quads x 4 batches = 64 batches
    int c0 = blockIdx.x * 128;
    float acc[4][4] = {};
    for (int dt = 0; dt < 8; ++dt) {
        __syncthreads();
        for (int e = tid; e < 2048; e += 512) {       // stage W_y tile (coalesced)
            int dd = e >> 5, c4 = e & 31;
            wsy[dd][c4] = *(const float4*)&W_y[(size_t)(dt * 64 + dd) * NV + c0 + c4 * 4];
        }
        for (int e = tid; e < 4096; e += 512) {       // stage os = tanh(sum op)
            int dd = e >> 6, bb = e & 63;
            int d = dt * 64 + dd;
            float sm = op[((size_t)0 * NB + bb) * ND + d] + op[((size_t)1 * NB + bb) * ND + d]
                     + op[((size_t)2 * NB + bb) * ND + d] + op[((size_t)3 * NB + bb) * ND + d];
            os[dd][bb] = tanhf(sm);
        }
        __syncthreads();
        for (int kk = 0; kk < 64; ++kk) {
            float4 wv = wsy[kk][cg];
            float4 ov = *(const float4*)&os[kk][bq * 4];
            acc[0][0] += ov.x * wv.x; acc[0][1] += ov.x * wv.y; acc[0][2] += ov.x * wv.z; acc[0][3] += ov.x * wv.w;
            acc[1][0] += ov.y * wv.x; acc[1][1] += ov.y * wv.y; acc[1][2] += ov.y * wv.z; acc[1][3] += ov.y * wv.w;
            acc[2][0] += ov.z * wv.x; acc[2][1] += ov.z * wv.y; acc[2][2] += ov.z * wv.z; acc[2][3] += ov.z * wv.w;
            acc[3][0] += ov.w * wv.x; acc[3][1] += ov.w * wv.y; acc[3][2] += ov.w * wv.z; acc[3][3] += ov.w * wv.w;
        }
    }
    #pragma unroll
    for (int i = 0; i < 4; ++i) {
        float4 st = make_float4(acc[i][0], acc[i][1], acc[i][2], acc[i][3]);
        *(float4*)&ylog[(size_t)(bq * 4 + i) * NV + c0 + cg * 4] = st;
    }
}

// ---------- softmax in place (registers) + out_f32 write (fused outfin) -----
__global__ void k_softmax(const float* __restrict__ op, float* __restrict__ out_f32,
                          float* __restrict__ y) {
    int b = blockIdx.x, tid = threadIdx.x, lane = tid & 63, wave = tid >> 6;
    if (tid < 512) {   // out = tanh(sum op) for this batch (same order as k_logits)
        float sm = op[((size_t)0 * NB + b) * ND + tid] + op[((size_t)1 * NB + b) * ND + tid]
                 + op[((size_t)2 * NB + b) * ND + tid] + op[((size_t)3 * NB + b) * ND + tid];
        out_f32[(size_t)b * ND + tid] = tanhf(sm);
    }
    float4* row = (float4*)(y + (size_t)b * NV);
    float4 r[8];
    int cnt = 0;
    for (int v4 = tid; v4 < NV4; v4 += 1024) r[cnt++] = row[v4];
    float m = -INFINITY;
    for (int k = 0; k < cnt; ++k)
        m = fmaxf(m, fmaxf(fmaxf(r[k].x, r[k].y), fmaxf(r[k].z, r[k].w)));
    #pragma unroll
    for (int off = 32; off > 0; off >>= 1) m = fmaxf(m, __shfl_xor(m, off, 64));
    __shared__ float red[16];
    __shared__ float bcast[2];
    if (lane == 0) red[wave] = m;
    __syncthreads();
    if (tid == 0) {
        float M = red[0];
        for (int w = 1; w < 16; ++w) M = fmaxf(M, red[w]);
        bcast[0] = M;
    }
    __syncthreads();
    float M = bcast[0];
    float s = 0.f;
    for (int k = 0; k < cnt; ++k) {
        r[k].x = __expf(r[k].x - M); r[k].y = __expf(r[k].y - M);
        r[k].z = __expf(r[k].z - M); r[k].w = __expf(r[k].w - M);
        s += r[k].x + r[k].y + r[k].z + r[k].w;
    }
    #pragma unroll
    for (int off = 32; off > 0; off >>= 1) s += __shfl_xor(s, off, 64);
    if (lane == 0) red[wave] = s;
    __syncthreads();
    if (tid == 0) {
        float S = 0.f;
        for (int w = 0; w < 16; ++w) S += red[w];
        bcast[1] = 1.f / S;
    }
    __syncthreads();
    float inv = bcast[1];
    cnt = 0;
    for (int v4 = tid; v4 < NV4; v4 += 1024) {
        float4 e4 = r[cnt++];
        e4.x *= inv; e4.y *= inv; e4.z *= inv; e4.w *= inv;
        row[v4] = e4;
    }
}

// ---------------------------------------------------------------------------
extern "C" void kernel_launch(void* const* d_in, const int* in_sizes, int n_in,
                              void* d_out, int out_size, void* d_ws, size_t ws_size,
                              hipStream_t stream) {
    (void)in_sizes; (void)n_in; (void)out_size; (void)ws_size;
    const float* featureGrid = (const float*)d_in[0];
    const float* y_prev      = (const float*)d_in[1];
    const float* out_prev    = (const float*)d_in[2];
    // d_in[3] = h_prev (unused by the reference)
    const float* c_prev      = (const float*)d_in[4];
    const float* embedding   = (const float*)d_in[5];
    const float* W_f = (const float*)d_in[6];
    const float* W_i = (const float*)d_in[7];
    const float* W_g = (const float*)d_in[8];
    const float* W_o = (const float*)d_in[9];
    const float* b_f = (const float*)d_in[10];
    const float* b_i = (const float*)d_in[11];
    const float* b_g = (const float*)d_in[12];
    const float* b_o = (const float*)d_in[13];
    const float* W_e   = (const float*)d_in[14];
    const float* W_out = (const float*)d_in[15];
    const float* W_y   = (const float*)d_in[16];

    // d_out: flat f32, return order: y [64*32000] | out [64*512] | h | c
    float* y_f32   = (float*)d_out;                 // 2,048,000 floats
    float* out_f32 = y_f32 + (size_t)NB * NV;       // 32768
    float* h_f32   = out_f32 + (size_t)NB * ND;     // 32768
    float* c_f32   = h_f32 + (size_t)NB * ND;       // 32768

    // Scratch in d_ws (~7 MB; ws is 2 GiB per the poison fills).
    float* ws = (float*)d_ws;
    int*   tok   = (int*)ws;                            // 64
    float* gp    = ws + 64;                             // 4ks*4g*64*512 = 524288
    float* wp    = gp + (size_t)GK_KS * 4 * NB * ND;    // 4*64*512 = 131072
    float* zctx  = wp + (size_t)WE_KS * NB * ND;        // 32768
    float* partM = zctx + NB * ND;                      // 2048
    float* partS = partM + NB * CHUNKS;                 // 2048
    float* partZ = partS + NB * CHUNKS;                 // 64*32*512 = 1048576
    float* op    = partZ + (size_t)NB * CHUNKS * ND;    // 4*64*512 = 131072

    k_argmax<<<NB, 1024, 0, stream>>>(y_prev, tok);
    k_gates<<<dim3(8, 4, GK_KS), 256, 0, stream>>>(embedding, out_prev, tok, W_f, W_i, W_g, W_o, gp);
    k_lstm<<<128, 256, 0, stream>>>(gp, c_prev, b_f, b_i, b_g, b_o, h_f32, c_f32);
    k_we<<<dim3(2, 4, WE_KS), 256, 0, stream>>>(h_f32, W_e, wp);
    k_attn<<<NB * CHUNKS, 256, 0, stream>>>(featureGrid, wp, partM, partS, partZ);
    k_zcomb<<<NB, 256, 0, stream>>>(partM, partS, partZ, zctx);
    k_wout<<<dim3(2, 4, WO_KS), 256, 0, stream>>>(h_f32, zctx, W_out, op);
    k_logits<<<250, 512, 0, stream>>>(op, W_y, y_f32);
    k_softmax<<<NB, 1024, 0, stream>>>(op, out_f32, y_f32);
}

// Round 8
// 328.437 us; speedup vs baseline: 1.0791x; 1.0791x over previous
//
#include <hip/hip_runtime.h>
#include <math.h>

#define NB 64
#define NL 4096
#define ND 512
#define NE 256
#define NV 32000
#define NX 768            // NE + ND
#define CHUNKS 32         // attention L-chunks per batch
#define RPC (NL / CHUNKS) // 128 rows per chunk
#define RPW (RPC / 4)     // 32 rows per wave
#define NV4 (NV / 4)      // 8000 float4 per vocab row

#define GK_KS 4           // k-split for gates (768 = 4*192)
#define GK_KL 192
#define WE_KS 4           // k-split for W_e   (512 = 4*128)
#define WE_KL 128
#define WO_KS 4           // k-split for W_out (1024 = 4*256)
#define WO_KL 256

// ---------------------------------------------------------------- argmax ----
__global__ void k_argmax(const float* __restrict__ y_prev, int* __restrict__ tok) {
    int b = blockIdx.x, tid = threadIdx.x, lane = tid & 63, wave = tid >> 6;
    const float4* row = (const float4*)(y_prev + (size_t)b * NV);
    float best = -INFINITY; int bi = 0x7fffffff;
    for (int v4 = tid; v4 < NV4; v4 += 1024) {
        float4 x = row[v4];
        int base = v4 * 4;
        if (x.x > best) { best = x.x; bi = base; }
        if (x.y > best) { best = x.y; bi = base + 1; }
        if (x.z > best) { best = x.z; bi = base + 2; }
        if (x.w > best) { best = x.w; bi = base + 3; }
    }
    #pragma unroll
    for (int off = 32; off > 0; off >>= 1) {
        float ob = __shfl_xor(best, off, 64);
        int   oi = __shfl_xor(bi, off, 64);
        if (ob > best || (ob == best && oi < bi)) { best = ob; bi = oi; }
    }
    __shared__ float sv[16]; __shared__ int si[16];
    if (lane == 0) { sv[wave] = best; si[wave] = bi; }
    __syncthreads();
    if (tid == 0) {
        float bb = sv[0]; int ii = si[0];
        for (int w = 1; w < 16; ++w)
            if (sv[w] > bb || (sv[w] == bb && si[w] < ii)) { bb = sv[w]; ii = si[w]; }
        tok[b] = ii;
    }
}

// ----------------------- gates GEMM, split-K, float4 W loads ----------------
__global__ void k_gates(const float* __restrict__ embedding, const float* __restrict__ out_prev,
                        const int* __restrict__ tok,
                        const float* __restrict__ W_f, const float* __restrict__ W_i,
                        const float* __restrict__ W_g, const float* __restrict__ W_o,
                        float* __restrict__ gp) {
    __shared__ float xs[16][GK_KL];
    int tid = threadIdx.x;
    int cc = blockIdx.x, bg = blockIdx.y, ks = blockIdx.z;
    int k0 = ks * GK_KL;
    for (int e = tid; e < 16 * GK_KL; e += 256) {
        int bi = e / GK_KL, kk = e - bi * GK_KL;
        int b = bg * 16 + bi, k = k0 + kk;
        xs[bi][kk] = (k < NE) ? embedding[(size_t)tok[b] * NE + k]
                              : out_prev[(size_t)b * ND + (k - NE)];
    }
    __syncthreads();
    int ct = tid & 63, bs = tid >> 6;
    int gate = cc >> 1;
    int d = (cc & 1) * 256 + ct * 4;
    const float* W = (gate == 0) ? W_f : (gate == 1) ? W_i : (gate == 2) ? W_g : W_o;
    const float4* Wp = (const float4*)(W + (size_t)k0 * ND + d);
    float acc[4][4] = {};
    #pragma unroll 4
    for (int kk = 0; kk < GK_KL; ++kk) {
        float4 w4 = Wp[kk * (ND / 4)];
        #pragma unroll
        for (int i = 0; i < 4; ++i) {
            float xv = xs[bs * 4 + i][kk];
            acc[i][0] += xv * w4.x; acc[i][1] += xv * w4.y;
            acc[i][2] += xv * w4.z; acc[i][3] += xv * w4.w;
        }
    }
    #pragma unroll
    for (int i = 0; i < 4; ++i) {
        int b = bg * 16 + bs * 4 + i;
        float4 st = make_float4(acc[i][0], acc[i][1], acc[i][2], acc[i][3]);
        *(float4*)&gp[(((size_t)ks * 4 + gate) * NB + b) * ND + d] = st;
    }
}

// ------------------------- LSTM pointwise + gate k-reduce -------------------
__global__ void k_lstm(const float* __restrict__ gp, const float* __restrict__ c_prev,
                       const float* __restrict__ b_f, const float* __restrict__ b_i,
                       const float* __restrict__ b_g, const float* __restrict__ b_o,
                       float* __restrict__ h_out, float* __restrict__ c_out) {
    int idx = blockIdx.x * 256 + threadIdx.x;  // 0..32767
    int b = idx >> 9, d = idx & 511;
    float F = b_f[d], I = b_i[d], G = b_g[d], O = b_o[d];
    #pragma unroll
    for (int ks = 0; ks < GK_KS; ++ks) {
        F += gp[(((size_t)ks * 4 + 0) * NB + b) * ND + d];
        I += gp[(((size_t)ks * 4 + 1) * NB + b) * ND + d];
        G += gp[(((size_t)ks * 4 + 2) * NB + b) * ND + d];
        O += gp[(((size_t)ks * 4 + 3) * NB + b) * ND + d];
    }
    float f = 1.f / (1.f + __expf(-F));
    float i = 1.f / (1.f + __expf(-I));
    float g = tanhf(G);
    float o = 1.f / (1.f + __expf(-O));
    float c = c_prev[idx] * f + i * g;
    float h = tanhf(c) * o;
    h_out[idx] = h;
    c_out[idx] = c;
}

// --------------------- b = h @ W_e, split-K, float4 W loads -----------------
__global__ void k_we(const float* __restrict__ h, const float* __restrict__ W_e,
                     float* __restrict__ wp) {
    __shared__ float hs[16][WE_KL];
    int tid = threadIdx.x;
    int cc = blockIdx.x, bg = blockIdx.y, ks = blockIdx.z;
    int k0 = ks * WE_KL;
    for (int e = tid; e < 16 * WE_KL; e += 256) {
        int bi = e >> 7, kk = e & 127;
        hs[bi][kk] = h[(size_t)(bg * 16 + bi) * ND + k0 + kk];
    }
    __syncthreads();
    int ct = tid & 63, bs = tid >> 6;
    int col = cc * 256 + ct * 4;
    const float4* Wp = (const float4*)(W_e + (size_t)k0 * ND + col);
    float acc[4][4] = {};
    #pragma unroll 4
    for (int kk = 0; kk < WE_KL; ++kk) {
        float4 w4 = Wp[kk * (ND / 4)];
        #pragma unroll
        for (int i = 0; i < 4; ++i) {
            float xv = hs[bs * 4 + i][kk];
            acc[i][0] += xv * w4.x; acc[i][1] += xv * w4.y;
            acc[i][2] += xv * w4.z; acc[i][3] += xv * w4.w;
        }
    }
    #pragma unroll
    for (int i = 0; i < 4; ++i) {
        int b = bg * 16 + bs * 4 + i;
        float4 st = make_float4(acc[i][0], acc[i][1], acc[i][2], acc[i][3]);
        *(float4*)&wp[((size_t)ks * NB + b) * ND + col] = st;
    }
}

// --------------------------- fused attention: online softmax + context ------
// grid NB*CHUNKS blocks, 256 thr (4 waves). featureGrid read exactly once.
// R6 structure (1 row/iter, 2-deep prefetch) + dense contiguous-half loads.
__global__ void k_attn(const float* __restrict__ fg, const float* __restrict__ wp,
                       float* __restrict__ partM, float* __restrict__ partS,
                       float* __restrict__ partZ) {
    int blk = blockIdx.x;
    int b = blk / CHUNKS, chunk = blk - b * CHUNKS;
    int tid = threadIdx.x, wave = tid >> 6, lane = tid & 63;
    int lo4 = lane * 4;
    float4 bs0 = make_float4(0.f, 0.f, 0.f, 0.f), bs1 = bs0;
    #pragma unroll
    for (int ks = 0; ks < WE_KS; ++ks) {
        const float* p = wp + ((size_t)ks * NB + b) * ND;
        float4 a = *(const float4*)(p + lo4);
        float4 c = *(const float4*)(p + 256 + lo4);
        bs0.x += a.x; bs0.y += a.y; bs0.z += a.z; bs0.w += a.w;
        bs1.x += c.x; bs1.y += c.y; bs1.z += c.z; bs1.w += c.w;
    }
    const float* rowp = fg + ((size_t)b * NL + (size_t)chunk * RPC + wave * RPW) * ND;
    float m = -INFINITY, s = 0.f;
    float z0 = 0, z1 = 0, z2 = 0, z3 = 0, z4 = 0, z5 = 0, z6 = 0, z7 = 0;
    // 2-deep row prefetch; v0 = dense low half [lo4,lo4+4), v1 = high half
    float4 c0v = *(const float4*)(rowp + lo4);
    float4 c1v = *(const float4*)(rowp + 256 + lo4);
    float4 n0v = *(const float4*)(rowp + ND + lo4);
    float4 n1v = *(const float4*)(rowp + ND + 256 + lo4);
    #pragma unroll 2
    for (int r = 0; r < RPW; ++r) {
        float4 v0 = c0v, v1 = c1v;
        c0v = n0v; c1v = n1v;
        if (r + 2 < RPW) {
            const float* np = rowp + 2 * ND;
            n0v = *(const float4*)(np + lo4);
            n1v = *(const float4*)(np + 256 + lo4);
        }
        float e = v0.x * bs0.x + v0.y * bs0.y + v0.z * bs0.z + v0.w * bs0.w
                + v1.x * bs1.x + v1.y * bs1.y + v1.z * bs1.z + v1.w * bs1.w;
        #pragma unroll
        for (int off = 32; off > 0; off >>= 1) e += __shfl_xor(e, off, 64);
        // e is bit-identical across lanes -> wave-uniform branch
        if (e > m) {
            float sc = __expf(m - e);    // m=-inf -> 0
            s *= sc;
            z0 *= sc; z1 *= sc; z2 *= sc; z3 *= sc;
            z4 *= sc; z5 *= sc; z6 *= sc; z7 *= sc;
            m = e;
        }
        float w = __expf(e - m);
        s += w;
        z0 += w * v0.x; z1 += w * v0.y; z2 += w * v0.z; z3 += w * v0.w;
        z4 += w * v1.x; z5 += w * v1.y; z6 += w * v1.z; z7 += w * v1.w;
        rowp += ND;
    }
    __shared__ float wm[4], wsum[4], wz[4][ND];
    float* zp = &wz[wave][0];
    zp[lo4 + 0] = z0; zp[lo4 + 1] = z1; zp[lo4 + 2] = z2; zp[lo4 + 3] = z3;
    zp[256 + lo4 + 0] = z4; zp[256 + lo4 + 1] = z5; zp[256 + lo4 + 2] = z6; zp[256 + lo4 + 3] = z7;
    if (lane == 0) { wm[wave] = m; wsum[wave] = s; }
    __syncthreads();
    float M = fmaxf(fmaxf(wm[0], wm[1]), fmaxf(wm[2], wm[3]));
    float e0 = __expf(wm[0] - M), e1 = __expf(wm[1] - M), e2 = __expf(wm[2] - M), e3 = __expf(wm[3] - M);
    if (tid == 0) {
        partM[blk] = M;
        partS[blk] = wsum[0] * e0 + wsum[1] * e1 + wsum[2] * e2 + wsum[3] * e3;
    }
    for (int d = tid; d < ND; d += 256)
        partZ[(size_t)blk * ND + d] = wz[0][d] * e0 + wz[1][d] * e1 + wz[2][d] * e2 + wz[3][d] * e3;
}

// ---------------------------------------------- combine chunk partials → z --
__global__ void k_zcomb(const float* __restrict__ partM, const float* __restrict__ partS,
                        const float* __restrict__ partZ, float* __restrict__ z) {
    int b = blockIdx.x, tid = threadIdx.x;
    float M = -INFINITY;
    #pragma unroll
    for (int j = 0; j < CHUNKS; ++j) M = fmaxf(M, partM[b * CHUNKS + j]);
    float w[CHUNKS]; float S = 0.f;
    #pragma unroll
    for (int j = 0; j < CHUNKS; ++j) { w[j] = __expf(partM[b * CHUNKS + j] - M); S += partS[b * CHUNKS + j] * w[j]; }
    float inv = 1.f / S;
    for (int d = tid; d < ND; d += 256) {
        float acc = 0.f;
        #pragma unroll
        for (int j = 0; j < CHUNKS; ++j) acc += w[j] * partZ[((size_t)b * CHUNKS + j) * ND + d];
        z[(size_t)b * ND + d] = acc * inv;
    }
}

// ----------------- [h,z] @ W_out, split-K; writes opT[ks][d][b] -------------
__global__ void k_wout(const float* __restrict__ h, const float* __restrict__ z,
                       const float* __restrict__ W_out, float* __restrict__ opT) {
    __shared__ float hzs[16][WO_KL];
    int tid = threadIdx.x;
    int cc = blockIdx.x, bg = blockIdx.y, ks = blockIdx.z;
    int k0 = ks * WO_KL;
    for (int e = tid; e < 16 * WO_KL; e += 256) {
        int bi = e >> 8, kk = e & 255;
        int b = bg * 16 + bi, k = k0 + kk;
        hzs[bi][kk] = (k < ND) ? h[(size_t)b * ND + k] : z[(size_t)b * ND + (k - ND)];
    }
    __syncthreads();
    int ct = tid & 63, bs = tid >> 6;
    int col = cc * 256 + ct * 4;
    const float4* Wp = (const float4*)(W_out + (size_t)k0 * ND + col);
    float acc[4][4] = {};
    #pragma unroll 4
    for (int kk = 0; kk < WO_KL; ++kk) {
        float4 w4 = Wp[kk * (ND / 4)];
        #pragma unroll
        for (int i = 0; i < 4; ++i) {
            float xv = hzs[bs * 4 + i][kk];
            acc[i][0] += xv * w4.x; acc[i][1] += xv * w4.y;
            acc[i][2] += xv * w4.z; acc[i][3] += xv * w4.w;
        }
    }
    #pragma unroll
    for (int i = 0; i < 4; ++i) {
        int b = bg * 16 + bs * 4 + i;
        #pragma unroll
        for (int j = 0; j < 4; ++j)
            opT[((size_t)ks * ND + col + j) * NB + b] = acc[i][j];
    }
}

// --------------------------------------------- logits = out @ W_y -----------
// 250 blocks x 512 thr (8 waves). Thread tile 4b x 4c. os staged in LDS with
// fused opT-reduce + tanh; W_y register-prefetched 8 rows, 2-deep (pA/pB).
#define WLOAD(P, G0)                                                          \
    { _Pragma("unroll")                                                       \
      for (int u = 0; u < 8; ++u)                                             \
          P[u] = *(const float4*)(wbase + (size_t)((G0) * 8 + u) * NV); }

#define WCOMP(P, G0)                                                          \
    { _Pragma("unroll")                                                       \
      for (int u = 0; u < 8; ++u) {                                           \
          int dd = ((G0) & 7) * 8 + u;                                        \
          float4 ov = *(const float4*)&os[dd][bq * 4];                        \
          const float ob[4] = {ov.x, ov.y, ov.z, ov.w};                       \
          const float wj[4] = {P[u].x, P[u].y, P[u].z, P[u].w};               \
          _Pragma("unroll")                                                   \
          for (int i = 0; i < 4; ++i) {                                       \
              _Pragma("unroll")                                               \
              for (int j = 0; j < 4; ++j) acc[i][j] += ob[i] * wj[j];         \
          }                                                                   \
      } }

__global__ __launch_bounds__(512, 1) void k_logits(const float* __restrict__ opT,
                                                   const float* __restrict__ W_y,
                                                   float* __restrict__ ylog) {
    __shared__ float os[64][64];  // [dd][b]
    int tid = threadIdx.x;
    int cg = tid & 31;            // 32 col-groups x 4 cols = 128 cols
    int bq = tid >> 5;            // 16 batch-quads x 4 batches = 64 batches
    int c0 = blockIdx.x * 128;
    const float* wbase = W_y + c0 + cg * 4;
    float acc[4][4];
    #pragma unroll
    for (int i = 0; i < 4; ++i)
        #pragma unroll
        for (int j = 0; j < 4; ++j) acc[i][j] = 0.f;
    float4 pA[8], pB[8];
    WLOAD(pA, 0);
    for (int G = 0; G < 64; G += 2) {    // G = 8-row group of W_y (512 K rows)
        if ((G & 7) == 0) {              // restage os every 64-row K-tile
            __syncthreads();
            int dt = G >> 3;
            for (int e = tid; e < 4096; e += 512) {
                int dd = e >> 6, bb = e & 63;   // consecutive bb -> coalesced
                size_t base = (size_t)(dt * 64 + dd) * NB + bb;
                float sm = opT[(size_t)0 * ND * NB + base]
                         + opT[(size_t)1 * ND * NB + base]
                         + opT[(size_t)2 * ND * NB + base]
                         + opT[(size_t)3 * ND * NB + base];
                os[dd][bb] = tanhf(sm);
            }
            __syncthreads();
        }
        WLOAD(pB, G + 1);
        WCOMP(pA, G);
        if (G + 2 < 64) WLOAD(pA, G + 2);
        WCOMP(pB, G + 1);
    }
    #pragma unroll
    for (int i = 0; i < 4; ++i) {
        float4 st = make_float4(acc[i][0], acc[i][1], acc[i][2], acc[i][3]);
        *(float4*)&ylog[(size_t)(bq * 4 + i) * NV + c0 + cg * 4] = st;
    }
}

// ---------- softmax in place (registers) + fused out = tanh(sum opT) --------
__global__ void k_softmax(const float* __restrict__ opT, float* __restrict__ out_f32,
                          float* __restrict__ y) {
    int b = blockIdx.x, tid = threadIdx.x, lane = tid & 63, wave = tid >> 6;
    if (tid < 512) {   // same reduce order as k_logits staging -> identical bits
        float sm = opT[((size_t)0 * ND + tid) * NB + b]
                 + opT[((size_t)1 * ND + tid) * NB + b]
                 + opT[((size_t)2 * ND + tid) * NB + b]
                 + opT[((size_t)3 * ND + tid) * NB + b];
        out_f32[(size_t)b * ND + tid] = tanhf(sm);
    }
    float4* row = (float4*)(y + (size_t)b * NV);
    float4 r[8];
    int cnt = 0;
    for (int v4 = tid; v4 < NV4; v4 += 1024) r[cnt++] = row[v4];
    float m = -INFINITY;
    for (int k = 0; k < cnt; ++k)
        m = fmaxf(m, fmaxf(fmaxf(r[k].x, r[k].y), fmaxf(r[k].z, r[k].w)));
    #pragma unroll
    for (int off = 32; off > 0; off >>= 1) m = fmaxf(m, __shfl_xor(m, off, 64));
    __shared__ float red[16];
    __shared__ float bcast[2];
    if (lane == 0) red[wave] = m;
    __syncthreads();
    if (tid == 0) {
        float M = red[0];
        for (int w = 1; w < 16; ++w) M = fmaxf(M, red[w]);
        bcast[0] = M;
    }
    __syncthreads();
    float M = bcast[0];
    float s = 0.f;
    for (int k = 0; k < cnt; ++k) {
        r[k].x = __expf(r[k].x - M); r[k].y = __expf(r[k].y - M);
        r[k].z = __expf(r[k].z - M); r[k].w = __expf(r[k].w - M);
        s += r[k].x + r[k].y + r[k].z + r[k].w;
    }
    #pragma unroll
    for (int off = 32; off > 0; off >>= 1) s += __shfl_xor(s, off, 64);
    if (lane == 0) red[wave] = s;
    __syncthreads();
    if (tid == 0) {
        float S = 0.f;
        for (int w = 0; w < 16; ++w) S += red[w];
        bcast[1] = 1.f / S;
    }
    __syncthreads();
    float inv = bcast[1];
    cnt = 0;
    for (int v4 = tid; v4 < NV4; v4 += 1024) {
        float4 e4 = r[cnt++];
        e4.x *= inv; e4.y *= inv; e4.z *= inv; e4.w *= inv;
        row[v4] = e4;
    }
}

// ---------------------------------------------------------------------------
extern "C" void kernel_launch(void* const* d_in, const int* in_sizes, int n_in,
                              void* d_out, int out_size, void* d_ws, size_t ws_size,
                              hipStream_t stream) {
    (void)in_sizes; (void)n_in; (void)out_size; (void)ws_size;
    const float* featureGrid = (const float*)d_in[0];
    const float* y_prev      = (const float*)d_in[1];
    const float* out_prev    = (const float*)d_in[2];
    // d_in[3] = h_prev (unused by the reference)
    const float* c_prev      = (const float*)d_in[4];
    const float* embedding   = (const float*)d_in[5];
    const float* W_f = (const float*)d_in[6];
    const float* W_i = (const float*)d_in[7];
    const float* W_g = (const float*)d_in[8];
    const float* W_o = (const float*)d_in[9];
    const float* b_f = (const float*)d_in[10];
    const float* b_i = (const float*)d_in[11];
    const float* b_g = (const float*)d_in[12];
    const float* b_o = (const float*)d_in[13];
    const float* W_e   = (const float*)d_in[14];
    const float* W_out = (const float*)d_in[15];
    const float* W_y   = (const float*)d_in[16];

    // d_out: flat f32, return order: y [64*32000] | out [64*512] | h | c
    float* y_f32   = (float*)d_out;                 // 2,048,000 floats
    float* out_f32 = y_f32 + (size_t)NB * NV;       // 32768
    float* h_f32   = out_f32 + (size_t)NB * ND;     // 32768
    float* c_f32   = h_f32 + (size_t)NB * ND;       // 32768

    // Scratch in d_ws (~7 MB; ws is 2 GiB per the poison fills).
    float* ws = (float*)d_ws;
    int*   tok   = (int*)ws;                            // 64
    float* gp    = ws + 64;                             // 4ks*4g*64*512 = 524288
    float* wp    = gp + (size_t)GK_KS * 4 * NB * ND;    // 4*64*512 = 131072
    float* zctx  = wp + (size_t)WE_KS * NB * ND;        // 32768
    float* partM = zctx + NB * ND;                      // 2048
    float* partS = partM + NB * CHUNKS;                 // 2048
    float* partZ = partS + NB * CHUNKS;                 // 64*32*512 = 1048576
    float* opT   = partZ + (size_t)NB * CHUNKS * ND;    // 4*512*64 = 131072

    k_argmax<<<NB, 1024, 0, stream>>>(y_prev, tok);
    k_gates<<<dim3(8, 4, GK_KS), 256, 0, stream>>>(embedding, out_prev, tok, W_f, W_i, W_g, W_o, gp);
    k_lstm<<<128, 256, 0, stream>>>(gp, c_prev, b_f, b_i, b_g, b_o, h_f32, c_f32);
    k_we<<<dim3(2, 4, WE_KS), 256, 0, stream>>>(h_f32, W_e, wp);
    k_attn<<<NB * CHUNKS, 256, 0, stream>>>(featureGrid, wp, partM, partS, partZ);
    k_zcomb<<<NB, 256, 0, stream>>>(partM, partS, partZ, zctx);
    k_wout<<<dim3(2, 4, WO_KS), 256, 0, stream>>>(h_f32, zctx, W_out, opT);
    k_logits<<<250, 512, 0, stream>>>(opT, W_y, y_f32);
    k_softmax<<<NB, 1024, 0, stream>>>(opT, out_f32, y_f32);
}

// Round 9
// 243.944 us; speedup vs baseline: 1.4528x; 1.3464x over previous
//
#include <hip/hip_runtime.h>
#include <math.h>

#define NB 64
#define NL 4096
#define ND 512
#define NE 256
#define NV 32000
#define NX 768            // NE + ND
#define CHUNKS 32         // attention L-chunks per batch
#define RPC (NL / CHUNKS) // 128 rows per chunk
#define RPW (RPC / 4)     // 32 rows per wave
#define NV4 (NV / 4)      // 8000 float4 per vocab row

#define GK_KS 4           // k-split for gates (768 = 4*192)
#define GK_KL 192
#define WE_KS 4           // k-split for W_e   (512 = 4*128)
#define WE_KL 128
#define WO_KS 4           // k-split for W_out (1024 = 4*256)
#define WO_KL 256

typedef float v4f __attribute__((ext_vector_type(4)));
__device__ __forceinline__ float4 ntload4(const float* p) {
    v4f v = __builtin_nontemporal_load((const v4f*)p);
    return make_float4(v[0], v[1], v[2], v[3]);
}

// ---------------------------------------------------------------- argmax ----
__global__ void k_argmax(const float* __restrict__ y_prev, int* __restrict__ tok) {
    int b = blockIdx.x, tid = threadIdx.x, lane = tid & 63, wave = tid >> 6;
    const float4* row = (const float4*)(y_prev + (size_t)b * NV);
    float best = -INFINITY; int bi = 0x7fffffff;
    for (int v4 = tid; v4 < NV4; v4 += 1024) {
        float4 x = row[v4];
        int base = v4 * 4;
        if (x.x > best) { best = x.x; bi = base; }
        if (x.y > best) { best = x.y; bi = base + 1; }
        if (x.z > best) { best = x.z; bi = base + 2; }
        if (x.w > best) { best = x.w; bi = base + 3; }
    }
    #pragma unroll
    for (int off = 32; off > 0; off >>= 1) {
        float ob = __shfl_xor(best, off, 64);
        int   oi = __shfl_xor(bi, off, 64);
        if (ob > best || (ob == best && oi < bi)) { best = ob; bi = oi; }
    }
    __shared__ float sv[16]; __shared__ int si[16];
    if (lane == 0) { sv[wave] = best; si[wave] = bi; }
    __syncthreads();
    if (tid == 0) {
        float bb = sv[0]; int ii = si[0];
        for (int w = 1; w < 16; ++w)
            if (sv[w] > bb || (sv[w] == bb && si[w] < ii)) { bb = sv[w]; ii = si[w]; }
        tok[b] = ii;
    }
}

// ----------------------- gates GEMM, split-K, float4 W loads ----------------
__global__ void k_gates(const float* __restrict__ embedding, const float* __restrict__ out_prev,
                        const int* __restrict__ tok,
                        const float* __restrict__ W_f, const float* __restrict__ W_i,
                        const float* __restrict__ W_g, const float* __restrict__ W_o,
                        float* __restrict__ gp) {
    __shared__ float xs[16][GK_KL];
    int tid = threadIdx.x;
    int cc = blockIdx.x, bg = blockIdx.y, ks = blockIdx.z;
    int k0 = ks * GK_KL;
    for (int e = tid; e < 16 * GK_KL; e += 256) {
        int bi = e / GK_KL, kk = e - bi * GK_KL;
        int b = bg * 16 + bi, k = k0 + kk;
        xs[bi][kk] = (k < NE) ? embedding[(size_t)tok[b] * NE + k]
                              : out_prev[(size_t)b * ND + (k - NE)];
    }
    __syncthreads();
    int ct = tid & 63, bs = tid >> 6;
    int gate = cc >> 1;
    int d = (cc & 1) * 256 + ct * 4;
    const float* W = (gate == 0) ? W_f : (gate == 1) ? W_i : (gate == 2) ? W_g : W_o;
    const float4* Wp = (const float4*)(W + (size_t)k0 * ND + d);
    float acc[4][4] = {};
    #pragma unroll 4
    for (int kk = 0; kk < GK_KL; ++kk) {
        float4 w4 = Wp[kk * (ND / 4)];
        #pragma unroll
        for (int i = 0; i < 4; ++i) {
            float xv = xs[bs * 4 + i][kk];
            acc[i][0] += xv * w4.x; acc[i][1] += xv * w4.y;
            acc[i][2] += xv * w4.z; acc[i][3] += xv * w4.w;
        }
    }
    #pragma unroll
    for (int i = 0; i < 4; ++i) {
        int b = bg * 16 + bs * 4 + i;
        float4 st = make_float4(acc[i][0], acc[i][1], acc[i][2], acc[i][3]);
        *(float4*)&gp[(((size_t)ks * 4 + gate) * NB + b) * ND + d] = st;
    }
}

// ------------------------- LSTM pointwise + gate k-reduce -------------------
__global__ void k_lstm(const float* __restrict__ gp, const float* __restrict__ c_prev,
                       const float* __restrict__ b_f, const float* __restrict__ b_i,
                       const float* __restrict__ b_g, const float* __restrict__ b_o,
                       float* __restrict__ h_out, float* __restrict__ c_out) {
    int idx = blockIdx.x * 256 + threadIdx.x;  // 0..32767
    int b = idx >> 9, d = idx & 511;
    float F = b_f[d], I = b_i[d], G = b_g[d], O = b_o[d];
    #pragma unroll
    for (int ks = 0; ks < GK_KS; ++ks) {
        F += gp[(((size_t)ks * 4 + 0) * NB + b) * ND + d];
        I += gp[(((size_t)ks * 4 + 1) * NB + b) * ND + d];
        G += gp[(((size_t)ks * 4 + 2) * NB + b) * ND + d];
        O += gp[(((size_t)ks * 4 + 3) * NB + b) * ND + d];
    }
    float f = 1.f / (1.f + __expf(-F));
    float i = 1.f / (1.f + __expf(-I));
    float g = tanhf(G);
    float o = 1.f / (1.f + __expf(-O));
    float c = c_prev[idx] * f + i * g;
    float h = tanhf(c) * o;
    h_out[idx] = h;
    c_out[idx] = c;
}

// --------------------- b = h @ W_e, split-K, float4 W loads -----------------
__global__ void k_we(const float* __restrict__ h, const float* __restrict__ W_e,
                     float* __restrict__ wp) {
    __shared__ float hs[16][WE_KL];
    int tid = threadIdx.x;
    int cc = blockIdx.x, bg = blockIdx.y, ks = blockIdx.z;
    int k0 = ks * WE_KL;
    for (int e = tid; e < 16 * WE_KL; e += 256) {
        int bi = e >> 7, kk = e & 127;
        hs[bi][kk] = h[(size_t)(bg * 16 + bi) * ND + k0 + kk];
    }
    __syncthreads();
    int ct = tid & 63, bs = tid >> 6;
    int col = cc * 256 + ct * 4;
    const float4* Wp = (const float4*)(W_e + (size_t)k0 * ND + col);
    float acc[4][4] = {};
    #pragma unroll 4
    for (int kk = 0; kk < WE_KL; ++kk) {
        float4 w4 = Wp[kk * (ND / 4)];
        #pragma unroll
        for (int i = 0; i < 4; ++i) {
            float xv = hs[bs * 4 + i][kk];
            acc[i][0] += xv * w4.x; acc[i][1] += xv * w4.y;
            acc[i][2] += xv * w4.z; acc[i][3] += xv * w4.w;
        }
    }
    #pragma unroll
    for (int i = 0; i < 4; ++i) {
        int b = bg * 16 + bs * 4 + i;
        float4 st = make_float4(acc[i][0], acc[i][1], acc[i][2], acc[i][3]);
        *(float4*)&wp[((size_t)ks * NB + b) * ND + col] = st;
    }
}

// --------------------------- fused attention: online softmax + context ------
// grid NB*CHUNKS blocks, 256 thr (4 waves). featureGrid read exactly once,
// via non-temporal dense contiguous-half loads (lane*4 / 256+lane*4).
__global__ void k_attn(const float* __restrict__ fg, const float* __restrict__ wp,
                       float* __restrict__ partM, float* __restrict__ partS,
                       float* __restrict__ partZ) {
    int blk = blockIdx.x;
    int b = blk / CHUNKS, chunk = blk - b * CHUNKS;
    int tid = threadIdx.x, wave = tid >> 6, lane = tid & 63;
    int lo4 = lane * 4;
    float4 bs0 = make_float4(0.f, 0.f, 0.f, 0.f), bs1 = bs0;
    #pragma unroll
    for (int ks = 0; ks < WE_KS; ++ks) {
        const float* p = wp + ((size_t)ks * NB + b) * ND;
        float4 a = *(const float4*)(p + lo4);
        float4 c = *(const float4*)(p + 256 + lo4);
        bs0.x += a.x; bs0.y += a.y; bs0.z += a.z; bs0.w += a.w;
        bs1.x += c.x; bs1.y += c.y; bs1.z += c.z; bs1.w += c.w;
    }
    const float* rowp = fg + ((size_t)b * NL + (size_t)chunk * RPC + wave * RPW) * ND;
    float m = -INFINITY, s = 0.f;
    float z0 = 0, z1 = 0, z2 = 0, z3 = 0, z4 = 0, z5 = 0, z6 = 0, z7 = 0;
    // 2-deep row prefetch
    float4 c0v = ntload4(rowp + lo4);
    float4 c1v = ntload4(rowp + 256 + lo4);
    float4 n0v = ntload4(rowp + ND + lo4);
    float4 n1v = ntload4(rowp + ND + 256 + lo4);
    #pragma unroll 2
    for (int r = 0; r < RPW; ++r) {
        float4 v0 = c0v, v1 = c1v;
        c0v = n0v; c1v = n1v;
        if (r + 2 < RPW) {
            const float* np = rowp + 2 * ND;
            n0v = ntload4(np + lo4);
            n1v = ntload4(np + 256 + lo4);
        }
        float e = v0.x * bs0.x + v0.y * bs0.y + v0.z * bs0.z + v0.w * bs0.w
                + v1.x * bs1.x + v1.y * bs1.y + v1.z * bs1.z + v1.w * bs1.w;
        #pragma unroll
        for (int off = 32; off > 0; off >>= 1) e += __shfl_xor(e, off, 64);
        // e is bit-identical across lanes -> wave-uniform branch
        if (e > m) {
            float sc = __expf(m - e);    // m=-inf -> 0
            s *= sc;
            z0 *= sc; z1 *= sc; z2 *= sc; z3 *= sc;
            z4 *= sc; z5 *= sc; z6 *= sc; z7 *= sc;
            m = e;
        }
        float w = __expf(e - m);
        s += w;
        z0 += w * v0.x; z1 += w * v0.y; z2 += w * v0.z; z3 += w * v0.w;
        z4 += w * v1.x; z5 += w * v1.y; z6 += w * v1.z; z7 += w * v1.w;
        rowp += ND;
    }
    __shared__ float wm[4], wsum[4], wz[4][ND];
    float* zp = &wz[wave][0];
    zp[lo4 + 0] = z0; zp[lo4 + 1] = z1; zp[lo4 + 2] = z2; zp[lo4 + 3] = z3;
    zp[256 + lo4 + 0] = z4; zp[256 + lo4 + 1] = z5; zp[256 + lo4 + 2] = z6; zp[256 + lo4 + 3] = z7;
    if (lane == 0) { wm[wave] = m; wsum[wave] = s; }
    __syncthreads();
    float M = fmaxf(fmaxf(wm[0], wm[1]), fmaxf(wm[2], wm[3]));
    float e0 = __expf(wm[0] - M), e1 = __expf(wm[1] - M), e2 = __expf(wm[2] - M), e3 = __expf(wm[3] - M);
    if (tid == 0) {
        partM[blk] = M;
        partS[blk] = wsum[0] * e0 + wsum[1] * e1 + wsum[2] * e2 + wsum[3] * e3;
    }
    for (int d = tid; d < ND; d += 256)
        partZ[(size_t)blk * ND + d] = wz[0][d] * e0 + wz[1][d] * e1 + wz[2][d] * e2 + wz[3][d] * e3;
}

// ---------------------------------------------- combine chunk partials → z --
__global__ void k_zcomb(const float* __restrict__ partM, const float* __restrict__ partS,
                        const float* __restrict__ partZ, float* __restrict__ z) {
    int b = blockIdx.x, tid = threadIdx.x;
    float M = -INFINITY;
    #pragma unroll
    for (int j = 0; j < CHUNKS; ++j) M = fmaxf(M, partM[b * CHUNKS + j]);
    float w[CHUNKS]; float S = 0.f;
    #pragma unroll
    for (int j = 0; j < CHUNKS; ++j) { w[j] = __expf(partM[b * CHUNKS + j] - M); S += partS[b * CHUNKS + j] * w[j]; }
    float inv = 1.f / S;
    for (int d = tid; d < ND; d += 256) {
        float acc = 0.f;
        #pragma unroll
        for (int j = 0; j < CHUNKS; ++j) acc += w[j] * partZ[((size_t)b * CHUNKS + j) * ND + d];
        z[(size_t)b * ND + d] = acc * inv;
    }
}

// ----------------- [h,z] @ W_out, split-K, float4 op writes -----------------
__global__ void k_wout(const float* __restrict__ h, const float* __restrict__ z,
                       const float* __restrict__ W_out, float* __restrict__ op) {
    __shared__ float hzs[16][WO_KL];
    int tid = threadIdx.x;
    int cc = blockIdx.x, bg = blockIdx.y, ks = blockIdx.z;
    int k0 = ks * WO_KL;
    for (int e = tid; e < 16 * WO_KL; e += 256) {
        int bi = e >> 8, kk = e & 255;
        int b = bg * 16 + bi, k = k0 + kk;
        hzs[bi][kk] = (k < ND) ? h[(size_t)b * ND + k] : z[(size_t)b * ND + (k - ND)];
    }
    __syncthreads();
    int ct = tid & 63, bs = tid >> 6;
    int col = cc * 256 + ct * 4;
    const float4* Wp = (const float4*)(W_out + (size_t)k0 * ND + col);
    float acc[4][4] = {};
    #pragma unroll 4
    for (int kk = 0; kk < WO_KL; ++kk) {
        float4 w4 = Wp[kk * (ND / 4)];
        #pragma unroll
        for (int i = 0; i < 4; ++i) {
            float xv = hzs[bs * 4 + i][kk];
            acc[i][0] += xv * w4.x; acc[i][1] += xv * w4.y;
            acc[i][2] += xv * w4.z; acc[i][3] += xv * w4.w;
        }
    }
    #pragma unroll
    for (int i = 0; i < 4; ++i) {
        int b = bg * 16 + bs * 4 + i;
        float4 st = make_float4(acc[i][0], acc[i][1], acc[i][2], acc[i][3]);
        *(float4*)&op[((size_t)ks * NB + b) * ND + col] = st;
    }
}

// --------------- reduce + tanh -> out (output slot) and outT ---------------
__global__ void k_outfin(const float* __restrict__ op,
                         float* __restrict__ out_f32, float* __restrict__ outT) {
    int idx = blockIdx.x * 512 + threadIdx.x;  // 0..32767
    int b = idx >> 9, d = idx & 511;
    float s = 0.f;
    #pragma unroll
    for (int ks = 0; ks < WO_KS; ++ks) s += op[((size_t)ks * NB + b) * ND + d];
    float t = tanhf(s);
    out_f32[idx] = t;
    outT[(size_t)d * NB + b] = t;
}

// --------------------------------------------- logits = out @ W_y -----------
// 250 blocks x 512 thr (8 waves). Thread tile 4b x 4c. outT staged per K-tile
// in LDS; W_y register-prefetched 8 rows ahead, 2-deep pipeline (pA/pB).
#define WLOAD(P, G0)                                                          \
    { _Pragma("unroll")                                                       \
      for (int u = 0; u < 8; ++u)                                             \
          P[u] = *(const float4*)(wbase + (size_t)((G0) * 8 + u) * NV); }

#define WCOMP(P, G0)                                                          \
    { _Pragma("unroll")                                                       \
      for (int u = 0; u < 8; ++u) {                                           \
          int dd = ((G0) & 7) * 8 + u;                                        \
          float4 ov = *(const float4*)&os[dd][bq * 4];                        \
          const float ob[4] = {ov.x, ov.y, ov.z, ov.w};                       \
          const float wj[4] = {P[u].x, P[u].y, P[u].z, P[u].w};               \
          _Pragma("unroll")                                                   \
          for (int i = 0; i < 4; ++i) {                                       \
              _Pragma("unroll")                                               \
              for (int j = 0; j < 4; ++j) acc[i][j] += ob[i] * wj[j];         \
          }                                                                   \
      } }

__global__ __launch_bounds__(512, 1) void k_logits(const float* __restrict__ outT,
                                                   const float* __restrict__ W_y,
                                                   float* __restrict__ ylog) {
    __shared__ float os[64][64];  // [dd][b]
    int tid = threadIdx.x;
    int cg = tid & 31;            // 32 col-groups x 4 cols = 128 cols
    int bq = tid >> 5;            // 16 batch-quads x 4 batches = 64 batches
    int c0 = blockIdx.x * 128;
    const float* wbase = W_y + c0 + cg * 4;
    float acc[4][4];
    #pragma unroll
    for (int i = 0; i < 4; ++i)
        #pragma unroll
        for (int j = 0; j < 4; ++j) acc[i][j] = 0.f;
    float4 pA[8], pB[8];
    WLOAD(pA, 0);
    for (int G = 0; G < 64; G += 2) {    // G = 8-row group of W_y (512 K rows)
        if ((G & 7) == 0) {              // restage os every 64-row K-tile
            __syncthreads();
            int dt = G >> 3;
            for (int e = tid; e < 4096; e += 512) {
                int dd = e >> 6, bb = e & 63;
                os[dd][bb] = outT[(size_t)(dt * 64 + dd) * NB + bb];
            }
            __syncthreads();
        }
        WLOAD(pB, G + 1);
        WCOMP(pA, G);
        if (G + 2 < 64) WLOAD(pA, G + 2);
        WCOMP(pB, G + 1);
    }
    #pragma unroll
    for (int i = 0; i < 4; ++i) {
        float4 st = make_float4(acc[i][0], acc[i][1], acc[i][2], acc[i][3]);
        *(float4*)&ylog[(size_t)(bq * 4 + i) * NV + c0 + cg * 4] = st;
    }
}

// ------------------- softmax in place, row data held in registers -----------
__global__ void k_softmax(float* __restrict__ y) {
    int b = blockIdx.x, tid = threadIdx.x, lane = tid & 63, wave = tid >> 6;
    float4* row = (float4*)(y + (size_t)b * NV);
    float4 r[8];
    int cnt = 0;
    for (int v4 = tid; v4 < NV4; v4 += 1024) r[cnt++] = row[v4];
    float m = -INFINITY;
    for (int k = 0; k < cnt; ++k)
        m = fmaxf(m, fmaxf(fmaxf(r[k].x, r[k].y), fmaxf(r[k].z, r[k].w)));
    #pragma unroll
    for (int off = 32; off > 0; off >>= 1) m = fmaxf(m, __shfl_xor(m, off, 64));
    __shared__ float red[16];
    __shared__ float bcast[2];
    if (lane == 0) red[wave] = m;
    __syncthreads();
    if (tid == 0) {
        float M = red[0];
        for (int w = 1; w < 16; ++w) M = fmaxf(M, red[w]);
        bcast[0] = M;
    }
    __syncthreads();
    float M = bcast[0];
    float s = 0.f;
    for (int k = 0; k < cnt; ++k) {
        r[k].x = __expf(r[k].x - M); r[k].y = __expf(r[k].y - M);
        r[k].z = __expf(r[k].z - M); r[k].w = __expf(r[k].w - M);
        s += r[k].x + r[k].y + r[k].z + r[k].w;
    }
    #pragma unroll
    for (int off = 32; off > 0; off >>= 1) s += __shfl_xor(s, off, 64);
    if (lane == 0) red[wave] = s;
    __syncthreads();
    if (tid == 0) {
        float S = 0.f;
        for (int w = 0; w < 16; ++w) S += red[w];
        bcast[1] = 1.f / S;
    }
    __syncthreads();
    float inv = bcast[1];
    cnt = 0;
    for (int v4 = tid; v4 < NV4; v4 += 1024) {
        float4 e4 = r[cnt++];
        e4.x *= inv; e4.y *= inv; e4.z *= inv; e4.w *= inv;
        row[v4] = e4;
    }
}

// ---------------------------------------------------------------------------
extern "C" void kernel_launch(void* const* d_in, const int* in_sizes, int n_in,
                              void* d_out, int out_size, void* d_ws, size_t ws_size,
                              hipStream_t stream) {
    (void)in_sizes; (void)n_in; (void)out_size; (void)ws_size;
    const float* featureGrid = (const float*)d_in[0];
    const float* y_prev      = (const float*)d_in[1];
    const float* out_prev    = (const float*)d_in[2];
    // d_in[3] = h_prev (unused by the reference)
    const float* c_prev      = (const float*)d_in[4];
    const float* embedding   = (const float*)d_in[5];
    const float* W_f = (const float*)d_in[6];
    const float* W_i = (const float*)d_in[7];
    const float* W_g = (const float*)d_in[8];
    const float* W_o = (const float*)d_in[9];
    const float* b_f = (const float*)d_in[10];
    const float* b_i = (const float*)d_in[11];
    const float* b_g = (const float*)d_in[12];
    const float* b_o = (const float*)d_in[13];
    const float* W_e   = (const float*)d_in[14];
    const float* W_out = (const float*)d_in[15];
    const float* W_y   = (const float*)d_in[16];

    // d_out: flat f32, return order: y [64*32000] | out [64*512] | h | c
    float* y_f32   = (float*)d_out;                 // 2,048,000 floats
    float* out_f32 = y_f32 + (size_t)NB * NV;       // 32768
    float* h_f32   = out_f32 + (size_t)NB * ND;     // 32768
    float* c_f32   = h_f32 + (size_t)NB * ND;       // 32768

    // Scratch in d_ws (~7.4 MB; ws is 2 GiB per the poison fills).
    float* ws = (float*)d_ws;
    int*   tok   = (int*)ws;                            // 64
    float* gp    = ws + 64;                             // 4ks*4g*64*512 = 524288
    float* wp    = gp + (size_t)GK_KS * 4 * NB * ND;    // 4*64*512 = 131072
    float* zctx  = wp + (size_t)WE_KS * NB * ND;        // 32768
    float* partM = zctx + NB * ND;                      // 2048
    float* partS = partM + NB * CHUNKS;                 // 2048
    float* partZ = partS + NB * CHUNKS;                 // 64*32*512 = 1048576
    float* op    = partZ + (size_t)NB * CHUNKS * ND;    // 4*64*512 = 131072
    float* outT  = op + (size_t)WO_KS * NB * ND;        // 32768

    k_argmax<<<NB, 1024, 0, stream>>>(y_prev, tok);
    k_gates<<<dim3(8, 4, GK_KS), 256, 0, stream>>>(embedding, out_prev, tok, W_f, W_i, W_g, W_o, gp);
    k_lstm<<<128, 256, 0, stream>>>(gp, c_prev, b_f, b_i, b_g, b_o, h_f32, c_f32);
    k_we<<<dim3(2, 4, WE_KS), 256, 0, stream>>>(h_f32, W_e, wp);
    k_attn<<<NB * CHUNKS, 256, 0, stream>>>(featureGrid, wp, partM, partS, partZ);
    k_zcomb<<<NB, 256, 0, stream>>>(partM, partS, partZ, zctx);
    k_wout<<<dim3(2, 4, WO_KS), 256, 0, stream>>>(h_f32, zctx, W_out, op);
    k_outfin<<<64, 512, 0, stream>>>(op, out_f32, outT);
    k_logits<<<250, 512, 0, stream>>>(outT, W_y, y_f32);
    k_softmax<<<NB, 1024, 0, stream>>>(y_f32);
}